// Round 5
// baseline (721.700 us; speedup 1.0000x reference)
//
#include <hip/hip_runtime.h>

// 2-layer LSTM: B=2048, T=512, F=60, H=7, PyTorch gate order (i,f,g,o).
//
// TWO-PHASE:
//  Phase 1 (proj_kernel): A[bt][r] = bias0[r] + Wih0[r,:].x[bt,:]  (fp32,
//    117 MB in d_ws). Gate-per-lane: each half-wave-32 owns one (b,t) row,
//    lane g computes gate r=g (lanes 28..31 idle). Wih0 row in REGISTERS;
//    x read with uniform-address float4 loads (2 addrs/wave, L1-line reuse
//    across consecutive rows). No LDS, no barriers. Memory-bound.
//  Phase 2 (rec_kernel): wave = batch (2048 waves, 2/SIMD).
//    lanes 0..27  : layer0 gate rows, step t     (seed = A[b][t][r])
//    lanes 32..59 : layer1 gate rows, step t-1   (seed = bias1[r])
//    Per step: 1 prefetched 4B load + 2x dot7 + activation + 3 shfl gathers
//    + cell update + 14 readlane broadcasts. No LDS/barriers/spills.
// Falls back to the round-3 single kernel if ws_size < 117.4 MB.

#define B_ 2048
#define T_ 512
#define F_ 60
#define H_ 7
#define G4 28
#define BT_ (B_ * T_)
#define L2E 1.4426950408889634f
#define PD 8   // rec prefetch ring depth
#define RPB 128  // proj rows per block (32 per wave)

#if __has_builtin(__builtin_amdgcn_exp2f)
#define EXP2(x) __builtin_amdgcn_exp2f(x)
#else
#define EXP2(x) exp2f(x)
#endif

__device__ __forceinline__ float rcpf_(float v) { return __builtin_amdgcn_rcpf(v); }

__device__ __forceinline__ float bcast(float v, int srclane) {
    return __uint_as_float(__builtin_amdgcn_readlane(__float_as_uint(v), srclane));
}

__device__ __forceinline__ float dot7(const float* w, const float* h, float seed) {
    float m01 = fmaf(w[1], h[1], w[0] * h[0]);
    float m23 = fmaf(w[3], h[3], w[2] * h[2]);
    float m45 = fmaf(w[5], h[5], w[4] * h[4]);
    float m6  = fmaf(w[6], h[6], seed);
    return (m01 + m23) + (m45 + m6);
}

// ---------------------------------------------------------------- phase 1
__global__ __launch_bounds__(256)
void proj_kernel(const float* __restrict__ x, const float* __restrict__ Wih0,
                 const float* __restrict__ bih0, const float* __restrict__ bhh0,
                 float* __restrict__ A)
{
    const int lane = threadIdx.x & 63;
    const int wv   = threadIdx.x >> 6;      // wave in block, 0..3
    const int g    = lane & 31;
    const int r    = (g < G4) ? g : (G4 - 1);
    const int half = lane >> 5;             // 0/1: which row of the pair

    // lane's Wih0 row in registers (tiny, L2-cached, once per wave)
    float wg[F_];
    #pragma unroll
    for (int k = 0; k < F_; ++k) wg[k] = Wih0[r * F_ + k];
    const float bias = bih0[r] + bhh0[r];

    const int row0 = blockIdx.x * RPB + wv * 32 + half;

    #pragma unroll 4
    for (int p = 0; p < 16; ++p) {
        const int row = row0 + 2 * p;
        const float4* __restrict__ xp = (const float4*)(x + (size_t)row * F_);
        float4 q[15];
        #pragma unroll
        for (int j = 0; j < 15; ++j) q[j] = xp[j];   // uniform addr per half-wave

        float s0 = bias, s1 = 0.f, s2 = 0.f, s3 = 0.f;
        #pragma unroll
        for (int j = 0; j < 15; ++j) {
            s0 = fmaf(wg[4 * j + 0], q[j].x, s0);
            s1 = fmaf(wg[4 * j + 1], q[j].y, s1);
            s2 = fmaf(wg[4 * j + 2], q[j].z, s2);
            s3 = fmaf(wg[4 * j + 3], q[j].w, s3);
        }
        float a = (s0 + s1) + (s2 + s3);

        if (g < G4) A[(size_t)row * G4 + r] = a;
    }
}

// ---------------------------------------------------------------- phase 2
__global__ __launch_bounds__(256)
void rec_kernel(const float* __restrict__ A,
                const float* __restrict__ Whh0,
                const float* __restrict__ Wih1, const float* __restrict__ Whh1,
                const float* __restrict__ bih1, const float* __restrict__ bhh1,
                float* __restrict__ out)
{
    const int tid   = threadIdx.x;
    const int lane  = tid & 63;
    const bool isL1 = lane >= 32;
    const int g     = lane & 31;
    const int r     = (g < G4) ? g : (G4 - 1);
    const int b     = blockIdx.x * 4 + (tid >> 6);

    float wA[H_], wB[H_];
    #pragma unroll
    for (int v = 0; v < H_; ++v) {
        wA[v] = isL1 ? Wih1[r * H_ + v] : Whh0[r * H_ + v];
        wB[v] = isL1 ? Whh1[r * H_ + v] : 0.f;
    }
    const float bias1 = bih1[r] + bhh1[r];

    const bool isT = (r >= 2 * H_ && r < 3 * H_);   // cell gate -> tanh
    const float KK = isT ? (-2.f * L2E) : (-L2E);
    const float Aa = isT ? 2.f : 1.f;
    const float Ca = isT ? -1.f : 0.f;

    float h0v[H_] = {0, 0, 0, 0, 0, 0, 0};
    float h1v[H_] = {0, 0, 0, 0, 0, 0, 0};
    float c = 0.f, hnew = 0.f;

    const float* __restrict__ pa = A + (size_t)b * T_ * G4 + r;

    float buf[PD];
    #pragma unroll
    for (int i = 0; i < PD; ++i) buf[i] = pa[i * G4];

    for (int tt = 0; tt < T_; tt += PD) {
        #pragma unroll
        for (int s = 0; s < PD; ++s) {
            const int t = tt + s;
            const int tn = (t + PD < T_) ? (t + PD) : (T_ - 1);
            float nb = pa[(size_t)tn * G4];

            float seed = isL1 ? bias1 : buf[s];
            float a = dot7(wA, h0v, seed);
            a = dot7(wB, h1v, a);
            float act = fmaf(Aa, rcpf_(1.f + EXP2(KK * a)), Ca);

            float fg = __shfl(act, lane + 7, 64);
            float gg = __shfl(act, lane + 14, 64);
            float og = __shfl(act, lane + 21, 64);

            float cnew = fmaf(fg, c, act * gg);
            if (t == 0) cnew = isL1 ? 0.f : cnew;   // L1 phantom step
            c = cnew;
            float th = fmaf(2.f, rcpf_(1.f + EXP2(-2.f * L2E * c)), -1.f);
            hnew = og * th;

            #pragma unroll
            for (int v = 0; v < H_; ++v) h0v[v] = bcast(hnew, v);
            #pragma unroll
            for (int v = 0; v < H_; ++v) h1v[v] = bcast(hnew, 32 + v);

            buf[s] = nb;
        }
    }

    // epilogue: layer1 step T-1 (consumes h0(T-1), h1(T-2))
    {
        float a = dot7(wA, h0v, isL1 ? bias1 : 0.f);
        a = dot7(wB, h1v, a);
        float act = fmaf(Aa, rcpf_(1.f + EXP2(KK * a)), Ca);
        float fg = __shfl(act, lane + 7, 64);
        float gg = __shfl(act, lane + 14, 64);
        float og = __shfl(act, lane + 21, 64);
        c = fmaf(fg, c, act * gg);
        float th = fmaf(2.f, rcpf_(1.f + EXP2(-2.f * L2E * c)), -1.f);
        hnew = og * th;
    }

    if (isL1 && g < H_) out[(size_t)b * H_ + g] = hnew;
}

// ------------------------------------------- fallback (round-3 kernel, passing)
#define CH 16
#define NCH (T_ / CH)
#define F4 15
#define ROW4 (CH * F4)
#define BPB 4
#define TOT4 (BPB * ROW4)

__device__ __forceinline__ float proj32(const float* pw, const float4* rp, float seed) {
    float s0 = seed, s1 = 0.f, s2 = 0.f, s3 = 0.f;
    #pragma unroll
    for (int j = 0; j < 8; ++j) {
        float4 q = rp[j];
        s0 = fmaf(pw[4 * j + 0], q.x, s0);
        s1 = fmaf(pw[4 * j + 1], q.y, s1);
        s2 = fmaf(pw[4 * j + 2], q.z, s2);
        s3 = fmaf(pw[4 * j + 3], q.w, s3);
    }
    return (s0 + s1) + (s2 + s3);
}

__global__ __launch_bounds__(256, 2)
void lstm2_fallback(const float* __restrict__ x,
                    const float* __restrict__ Wih0, const float* __restrict__ Whh0,
                    const float* __restrict__ bih0, const float* __restrict__ bhh0,
                    const float* __restrict__ Wih1, const float* __restrict__ Whh1,
                    const float* __restrict__ bih1, const float* __restrict__ bhh1,
                    float* __restrict__ out)
{
    __shared__ float4 lds4[2][BPB][ROW4];

    const int tid   = threadIdx.x;
    const int lane  = tid & 63;
    const bool isL1 = lane >= 32;
    const int g     = lane & 31;
    const int r     = (g < G4) ? g : (G4 - 1);
    const int grp   = tid >> 6;
    const int b     = blockIdx.x * BPB + grp;

    float pw[32];
    {
        const int offs = isL1 ? 28 : 0;
        #pragma unroll
        for (int k = 0; k < 32; ++k) pw[k] = Wih0[r * F_ + offs + k];
        if (isL1) { pw[0] = pw[1] = pw[2] = pw[3] = 0.f; }
    }
    float wA[H_], wB[H_];
    #pragma unroll
    for (int v = 0; v < H_; ++v) {
        wA[v] = isL1 ? Wih1[r * H_ + v] : Whh0[r * H_ + v];
        wB[v] = isL1 ? Whh1[r * H_ + v] : 0.f;
    }
    const float bias0 = bih0[r] + bhh0[r];
    const float bias1 = bih1[r] + bhh1[r];

    const bool isT = (r >= 2 * H_ && r < 3 * H_);
    const float KK = isT ? (-2.f * L2E) : (-L2E);
    const float Aa = isT ? 2.f : 1.f;
    const float Ca = isT ? -1.f : 0.f;

    float h0v[H_] = {0, 0, 0, 0, 0, 0, 0};
    float h1v[H_] = {0, 0, 0, 0, 0, 0, 0};
    float c = 0.f, hnew = 0.f;

    const float4* __restrict__ xb =
        (const float4*)(x + (size_t)(blockIdx.x * BPB) * T_ * F_);
    const int XB4 = T_ * F4;
    const int lofs = isL1 ? 7 : 0;
    const float pseed = isL1 ? 0.f : bias0;

    #pragma unroll
    for (int i = 0; i < 4; ++i) {
        int idx = tid + 256 * i;
        if (idx < TOT4) {
            int bl = idx / ROW4;
            int j  = idx - bl * ROW4;
            lds4[0][bl][j] = xb[bl * XB4 + j];
        }
    }
    __syncthreads();

    float a_in;
    {
        float ow = proj32(pw, &lds4[0][grp][0] + lofs, pseed);
        a_in = ow + __shfl(ow, lane ^ 32, 64);
    }

    for (int ch = 0; ch < NCH; ++ch) {
        const int cn = (ch < NCH - 1) ? ch + 1 : ch;
        float4 st[4];
        #pragma unroll
        for (int i = 0; i < 4; ++i) {
            int idx = tid + 256 * i;
            if (idx < TOT4) {
                int bl = idx / ROW4;
                int j  = idx - bl * ROW4;
                st[i] = xb[bl * XB4 + cn * ROW4 + j];
            }
        }

        const int buf = ch & 1;
        const float4* __restrict__ rowb = &lds4[buf][grp][0] + lofs;

        #pragma unroll
        for (int s = 0; s < CH; ++s) {
            float seed = isL1 ? bias1 : a_in;
            float a = dot7(wA, h0v, seed);
            a = dot7(wB, h1v, a);
            float act = fmaf(Aa, rcpf_(1.f + EXP2(KK * a)), Ca);

            float fg = __shfl(act, lane + 7, 64);
            float gg = __shfl(act, lane + 14, 64);
            float og = __shfl(act, lane + 21, 64);

            float cnew = fmaf(fg, c, act * gg);
            if (ch == 0 && s == 0) cnew = isL1 ? 0.f : cnew;
            c = cnew;
            float th = fmaf(2.f, rcpf_(1.f + EXP2(-2.f * L2E * c)), -1.f);
            hnew = og * th;

            #pragma unroll
            for (int v = 0; v < H_; ++v) h0v[v] = bcast(hnew, v);
            if (ch > 0 || s > 0) {
                #pragma unroll
                for (int v = 0; v < H_; ++v) h1v[v] = bcast(hnew, 32 + v);
            }

            if (s < CH - 1) {
                float ow = proj32(pw, rowb + (s + 1) * F4, pseed);
                a_in = ow + __shfl(ow, lane ^ 32, 64);
            }
        }

        #pragma unroll
        for (int i = 0; i < 4; ++i) {
            int idx = tid + 256 * i;
            if (idx < TOT4) {
                int bl = idx / ROW4;
                int j  = idx - bl * ROW4;
                lds4[buf ^ 1][bl][j] = st[i];
            }
        }
        __syncthreads();

        if (ch < NCH - 1) {
            float ow = proj32(pw, &lds4[buf ^ 1][grp][0] + lofs, pseed);
            a_in = ow + __shfl(ow, lane ^ 32, 64);
        }
    }

    {
        float a = dot7(wA, h0v, isL1 ? bias1 : 0.f);
        a = dot7(wB, h1v, a);
        float act = fmaf(Aa, rcpf_(1.f + EXP2(KK * a)), Ca);
        float fg = __shfl(act, lane + 7, 64);
        float gg = __shfl(act, lane + 14, 64);
        float og = __shfl(act, lane + 21, 64);
        c = fmaf(fg, c, act * gg);
        float th = fmaf(2.f, rcpf_(1.f + EXP2(-2.f * L2E * c)), -1.f);
        hnew = og * th;
    }

    if (isL1 && g < H_) out[(size_t)b * H_ + g] = hnew;
}

extern "C" void kernel_launch(void* const* d_in, const int* in_sizes, int n_in,
                              void* d_out, int out_size, void* d_ws, size_t ws_size,
                              hipStream_t stream) {
    const float* x    = (const float*)d_in[0];
    const float* Wih0 = (const float*)d_in[1];
    const float* Whh0 = (const float*)d_in[2];
    const float* bih0 = (const float*)d_in[3];
    const float* bhh0 = (const float*)d_in[4];
    const float* Wih1 = (const float*)d_in[5];
    const float* Whh1 = (const float*)d_in[6];
    const float* bih1 = (const float*)d_in[7];
    const float* bhh1 = (const float*)d_in[8];
    float* out = (float*)d_out;

    const size_t need = (size_t)BT_ * G4 * sizeof(float);   // 117,440,512 B
    if (ws_size >= need) {
        float* A = (float*)d_ws;
        proj_kernel<<<dim3(BT_ / RPB), dim3(256), 0, stream>>>(x, Wih0, bih0, bhh0, A);
        rec_kernel<<<dim3(B_ / 4), dim3(256), 0, stream>>>(A, Whh0, Wih1, Whh1,
                                                           bih1, bhh1, out);
    } else {
        lstm2_fallback<<<dim3(B_ / BPB), dim3(256), 0, stream>>>(
            x, Wih0, Whh0, bih0, bhh0, Wih1, Whh1, bih1, bhh1, out);
    }
}

// Round 6
// 668.465 us; speedup vs baseline: 1.0796x; 1.0796x over previous
//
#include <hip/hip_runtime.h>

// 2-layer LSTM: B=2048, T=512, F=60, H=7, PyTorch gate order (i,f,g,o).
//
// TWO-PHASE:
//  Phase 1 (proj_kernel): A'[bt][4u+gi] = bias0[r] + Wih0[r,:].x[bt,:],
//    r = gi*7+u (UNIT-INTERLEAVED layout so rec's quad = one unit's i,f,g,o).
//    4 rows per thread, acc[28][4] in registers; weights streamed from LDS
//    once per j (28 uniform b128 reads serve 4 rows -> LDS cost /4 vs r4);
//    x loaded direct from global, prefetched one j ahead (448 FMA/j covers
//    HBM latency). No spills (acc 112 + q 32 + misc ~ 160 VGPR).
//  Phase 2 (rec_kernel): wave = batch (2048 waves, 2/SIMD).
//    lane = (L1?32:0) + 4*u + gate; layer1 runs one step behind layer0
//    (pipelined on lanes). Gate gathers are intra-quad DPP broadcasts
//    (VALU pipe, ~4cyc) instead of ds_bpermute (~120cyc) -> short chain.
//    h broadcasts via v_readlane (SGPRs). A seeds prefetched 8 steps ahead.
// Falls back to the round-3 single kernel if ws_size < 117.4 MB.

#define B_ 2048
#define T_ 512
#define F_ 60
#define H_ 7
#define G4 28
#define BT_ (B_ * T_)
#define L2E 1.4426950408889634f
#define PD 8               // rec prefetch depth (steps)
#define RPT 4              // proj rows per thread
#define PRB (256 * RPT)    // proj rows per block = 1024

#if __has_builtin(__builtin_amdgcn_exp2f)
#define EXP2(x) __builtin_amdgcn_exp2f(x)
#else
#define EXP2(x) exp2f(x)
#endif

// intra-quad broadcast: every lane of a 4-lane quad gets quad-lane `pat`
#define QUADB(v, pat) \
    __int_as_float(__builtin_amdgcn_mov_dpp(__float_as_int(v), pat, 0xF, 0xF, true))

__device__ __forceinline__ float rcpf_(float v) { return __builtin_amdgcn_rcpf(v); }

__device__ __forceinline__ float bcast(float v, int srclane) {
    return __uint_as_float(__builtin_amdgcn_readlane(__float_as_uint(v), srclane));
}

__device__ __forceinline__ float dot7(const float* w, const float* h, float seed) {
    float m01 = fmaf(w[1], h[1], w[0] * h[0]);
    float m23 = fmaf(w[3], h[3], w[2] * h[2]);
    float m45 = fmaf(w[5], h[5], w[4] * h[4]);
    float m6  = fmaf(w[6], h[6], seed);
    return (m01 + m23) + (m45 + m6);
}

// ---------------------------------------------------------------- phase 1
__global__ __launch_bounds__(256)
void proj_kernel(const float* __restrict__ x, const float* __restrict__ Wih0,
                 const float* __restrict__ bih0, const float* __restrict__ bhh0,
                 float* __restrict__ A)
{
    __shared__ float4 wsm4[G4 * 15];   // Wih0 as float4 rows (6720 B)
    __shared__ float  bsm[G4];

    const int tid = threadIdx.x;
    for (int i = tid; i < G4 * 15; i += 256) wsm4[i] = ((const float4*)Wih0)[i];
    if (tid < G4) bsm[tid] = bih0[tid] + bhh0[tid];
    __syncthreads();

    const int row0 = blockIdx.x * PRB + tid;   // thread's rows: row0 + 256*rr

    float acc[G4][RPT];
    #pragma unroll
    for (int p = 0; p < G4; ++p) {
        const int r = (p & 3) * 7 + (p >> 2);
        const float bb = bsm[r];
        #pragma unroll
        for (int rr = 0; rr < RPT; ++rr) acc[p][rr] = bb;
    }

    const float* bp[RPT];
    #pragma unroll
    for (int rr = 0; rr < RPT; ++rr) bp[rr] = x + (size_t)(row0 + 256 * rr) * F_;

    float4 qc[RPT], qn[RPT];
    #pragma unroll
    for (int rr = 0; rr < RPT; ++rr) qc[rr] = *(const float4*)(bp[rr]);

    #pragma unroll 1
    for (int j = 0; j < 15; ++j) {
        const int jn = (j < 14) ? j + 1 : 14;   // clamped reload on last iter
        #pragma unroll
        for (int rr = 0; rr < RPT; ++rr)
            qn[rr] = *(const float4*)(bp[rr] + 4 * jn);

        #pragma unroll
        for (int p = 0; p < G4; ++p) {
            const int r = (p & 3) * 7 + (p >> 2);
            float4 w = wsm4[r * 15 + j];        // uniform broadcast read
            #pragma unroll
            for (int rr = 0; rr < RPT; ++rr) {
                acc[p][rr] = fmaf(w.x, qc[rr].x, acc[p][rr]);
                acc[p][rr] = fmaf(w.y, qc[rr].y, acc[p][rr]);
                acc[p][rr] = fmaf(w.z, qc[rr].z, acc[p][rr]);
                acc[p][rr] = fmaf(w.w, qc[rr].w, acc[p][rr]);
            }
        }
        #pragma unroll
        for (int rr = 0; rr < RPT; ++rr) qc[rr] = qn[rr];
    }

    #pragma unroll
    for (int rr = 0; rr < RPT; ++rr) {
        float4* __restrict__ Ap = (float4*)(A + (size_t)(row0 + 256 * rr) * G4);
        #pragma unroll
        for (int u = 0; u < 7; ++u)
            Ap[u] = make_float4(acc[4 * u + 0][rr], acc[4 * u + 1][rr],
                                acc[4 * u + 2][rr], acc[4 * u + 3][rr]);
    }
}

// ---------------------------------------------------------------- phase 2
__global__ __launch_bounds__(256)
void rec_kernel(const float* __restrict__ A,
                const float* __restrict__ Whh0,
                const float* __restrict__ Wih1, const float* __restrict__ Whh1,
                const float* __restrict__ bih1, const float* __restrict__ bhh1,
                float* __restrict__ out)
{
    const int tid  = threadIdx.x;
    const int lane = tid & 63;
    const bool isL1 = lane >= 32;
    const int l5 = lane & 31;
    const int gi = lane & 3;              // gate within unit: 0=i 1=f 2=g 3=o
    const int u  = l5 >> 2;               // unit 0..6 (7 = idle lanes 28..31)
    const int r  = min(gi * 7 + u, G4 - 1);   // original gate-row index
    const int pos = min(l5, G4 - 1);          // A' column (clamped for idles)
    const int b  = blockIdx.x * 4 + (tid >> 6);

    float wA[H_], wB[H_];
    #pragma unroll
    for (int v = 0; v < H_; ++v) {
        wA[v] = isL1 ? Wih1[r * H_ + v] : Whh0[r * H_ + v];
        wB[v] = isL1 ? Whh1[r * H_ + v] : 0.f;
    }
    const float bias1 = bih1[r] + bhh1[r];

    const bool isT = (gi == 2);           // cell gate -> tanh
    const float KK = isT ? (-2.f * L2E) : (-L2E);
    const float Aa = isT ? 2.f : 1.f;
    const float Ca = isT ? -1.f : 0.f;

    float h0v[H_] = {0, 0, 0, 0, 0, 0, 0};   // wave-uniform (SGPRs)
    float h1v[H_] = {0, 0, 0, 0, 0, 0, 0};
    float c = 0.f, hnew = 0.f;

    const float* __restrict__ pa = A + (size_t)b * T_ * G4 + pos;

    float buf[PD], nxt[PD];
    #pragma unroll
    for (int i = 0; i < PD; ++i) buf[i] = pa[(size_t)i * G4];

    #pragma unroll 1
    for (int tt = 0; tt < T_; tt += PD) {
        const bool more = (tt + PD < T_);
        if (more) {
            #pragma unroll
            for (int i = 0; i < PD; ++i) nxt[i] = pa[(size_t)(tt + PD + i) * G4];
        }
        #pragma unroll
        for (int s = 0; s < PD; ++s) {
            // unified gate preactivation (L0 step tt+s, L1 step tt+s-1)
            float seed = isL1 ? bias1 : buf[s];
            float a = dot7(wA, h0v, seed);
            a = dot7(wB, h1v, a);
            float act = fmaf(Aa, rcpf_(1.f + EXP2(KK * a)), Ca);

            // intra-quad gather of i,f,g,o (VALU DPP, no DS pipe)
            float vi = QUADB(act, 0x00);
            float vf = QUADB(act, 0x55);
            float vg = QUADB(act, 0xAA);
            float vo = QUADB(act, 0xFF);

            float cnew = fmaf(vf, c, vi * vg);
            if (tt == 0 && s == 0) cnew = isL1 ? 0.f : cnew;  // L1 phantom step
            c = cnew;
            float th = fmaf(2.f, rcpf_(1.f + EXP2(-2.f * L2E * c)), -1.f);
            hnew = vo * th;   // uniform within quad; h1(t=0) = 0 automatically

            #pragma unroll
            for (int v = 0; v < H_; ++v) h0v[v] = bcast(hnew, 4 * v);
            #pragma unroll
            for (int v = 0; v < H_; ++v) h1v[v] = bcast(hnew, 32 + 4 * v);
        }
        if (more) {
            #pragma unroll
            for (int i = 0; i < PD; ++i) buf[i] = nxt[i];
        }
    }

    // epilogue: layer1 step T-1 (consumes h0(T-1), h1(T-2))
    {
        float a = dot7(wA, h0v, isL1 ? bias1 : 0.f);
        a = dot7(wB, h1v, a);
        float act = fmaf(Aa, rcpf_(1.f + EXP2(KK * a)), Ca);
        float vi = QUADB(act, 0x00);
        float vf = QUADB(act, 0x55);
        float vg = QUADB(act, 0xAA);
        float vo = QUADB(act, 0xFF);
        c = fmaf(vf, c, vi * vg);
        float th = fmaf(2.f, rcpf_(1.f + EXP2(-2.f * L2E * c)), -1.f);
        hnew = vo * th;
    }

    if (isL1 && gi == 0 && u < H_) out[(size_t)b * H_ + u] = hnew;
}

// ------------------------------------------- fallback (round-3 kernel, passing)
#define CH 16
#define NCH (T_ / CH)
#define F4 15
#define ROW4 (CH * F4)
#define BPB 4
#define TOT4 (BPB * ROW4)

__device__ __forceinline__ float proj32(const float* pw, const float4* rp, float seed) {
    float s0 = seed, s1 = 0.f, s2 = 0.f, s3 = 0.f;
    #pragma unroll
    for (int j = 0; j < 8; ++j) {
        float4 q = rp[j];
        s0 = fmaf(pw[4 * j + 0], q.x, s0);
        s1 = fmaf(pw[4 * j + 1], q.y, s1);
        s2 = fmaf(pw[4 * j + 2], q.z, s2);
        s3 = fmaf(pw[4 * j + 3], q.w, s3);
    }
    return (s0 + s1) + (s2 + s3);
}

__global__ __launch_bounds__(256, 2)
void lstm2_fallback(const float* __restrict__ x,
                    const float* __restrict__ Wih0, const float* __restrict__ Whh0,
                    const float* __restrict__ bih0, const float* __restrict__ bhh0,
                    const float* __restrict__ Wih1, const float* __restrict__ Whh1,
                    const float* __restrict__ bih1, const float* __restrict__ bhh1,
                    float* __restrict__ out)
{
    __shared__ float4 lds4[2][BPB][ROW4];

    const int tid   = threadIdx.x;
    const int lane  = tid & 63;
    const bool isL1 = lane >= 32;
    const int g     = lane & 31;
    const int r     = (g < G4) ? g : (G4 - 1);
    const int grp   = tid >> 6;
    const int b     = blockIdx.x * BPB + grp;

    float pw[32];
    {
        const int offs = isL1 ? 28 : 0;
        #pragma unroll
        for (int k = 0; k < 32; ++k) pw[k] = Wih0[r * F_ + offs + k];
        if (isL1) { pw[0] = pw[1] = pw[2] = pw[3] = 0.f; }
    }
    float wA[H_], wB[H_];
    #pragma unroll
    for (int v = 0; v < H_; ++v) {
        wA[v] = isL1 ? Wih1[r * H_ + v] : Whh0[r * H_ + v];
        wB[v] = isL1 ? Whh1[r * H_ + v] : 0.f;
    }
    const float bias0 = bih0[r] + bhh0[r];
    const float bias1 = bih1[r] + bhh1[r];

    const bool isT = (r >= 2 * H_ && r < 3 * H_);
    const float KK = isT ? (-2.f * L2E) : (-L2E);
    const float Aa = isT ? 2.f : 1.f;
    const float Ca = isT ? -1.f : 0.f;

    float h0v[H_] = {0, 0, 0, 0, 0, 0, 0};
    float h1v[H_] = {0, 0, 0, 0, 0, 0, 0};
    float c = 0.f, hnew = 0.f;

    const float4* __restrict__ xb =
        (const float4*)(x + (size_t)(blockIdx.x * BPB) * T_ * F_);
    const int XB4 = T_ * F4;
    const int lofs = isL1 ? 7 : 0;
    const float pseed = isL1 ? 0.f : bias0;

    #pragma unroll
    for (int i = 0; i < 4; ++i) {
        int idx = tid + 256 * i;
        if (idx < TOT4) {
            int bl = idx / ROW4;
            int j  = idx - bl * ROW4;
            lds4[0][bl][j] = xb[bl * XB4 + j];
        }
    }
    __syncthreads();

    float a_in;
    {
        float ow = proj32(pw, &lds4[0][grp][0] + lofs, pseed);
        a_in = ow + __shfl(ow, lane ^ 32, 64);
    }

    for (int ch = 0; ch < NCH; ++ch) {
        const int cn = (ch < NCH - 1) ? ch + 1 : ch;
        float4 st[4];
        #pragma unroll
        for (int i = 0; i < 4; ++i) {
            int idx = tid + 256 * i;
            if (idx < TOT4) {
                int bl = idx / ROW4;
                int j  = idx - bl * ROW4;
                st[i] = xb[bl * XB4 + cn * ROW4 + j];
            }
        }

        const int buf = ch & 1;
        const float4* __restrict__ rowb = &lds4[buf][grp][0] + lofs;

        #pragma unroll
        for (int s = 0; s < CH; ++s) {
            float seed = isL1 ? bias1 : a_in;
            float a = dot7(wA, h0v, seed);
            a = dot7(wB, h1v, a);
            float act = fmaf(Aa, rcpf_(1.f + EXP2(KK * a)), Ca);

            float fg = __shfl(act, lane + 7, 64);
            float gg = __shfl(act, lane + 14, 64);
            float og = __shfl(act, lane + 21, 64);

            float cnew = fmaf(fg, c, act * gg);
            if (ch == 0 && s == 0) cnew = isL1 ? 0.f : cnew;
            c = cnew;
            float th = fmaf(2.f, rcpf_(1.f + EXP2(-2.f * L2E * c)), -1.f);
            hnew = og * th;

            #pragma unroll
            for (int v = 0; v < H_; ++v) h0v[v] = bcast(hnew, v);
            if (ch > 0 || s > 0) {
                #pragma unroll
                for (int v = 0; v < H_; ++v) h1v[v] = bcast(hnew, 32 + v);
            }

            if (s < CH - 1) {
                float ow = proj32(pw, rowb + (s + 1) * F4, pseed);
                a_in = ow + __shfl(ow, lane ^ 32, 64);
            }
        }

        #pragma unroll
        for (int i = 0; i < 4; ++i) {
            int idx = tid + 256 * i;
            if (idx < TOT4) {
                int bl = idx / ROW4;
                int j  = idx - bl * ROW4;
                lds4[buf ^ 1][bl][j] = st[i];
            }
        }
        __syncthreads();

        if (ch < NCH - 1) {
            float ow = proj32(pw, &lds4[buf ^ 1][grp][0] + lofs, pseed);
            a_in = ow + __shfl(ow, lane ^ 32, 64);
        }
    }

    {
        float a = dot7(wA, h0v, isL1 ? bias1 : 0.f);
        a = dot7(wB, h1v, a);
        float act = fmaf(Aa, rcpf_(1.f + EXP2(KK * a)), Ca);
        float fg = __shfl(act, lane + 7, 64);
        float gg = __shfl(act, lane + 14, 64);
        float og = __shfl(act, lane + 21, 64);
        c = fmaf(fg, c, act * gg);
        float th = fmaf(2.f, rcpf_(1.f + EXP2(-2.f * L2E * c)), -1.f);
        hnew = og * th;
    }

    if (isL1 && g < H_) out[(size_t)b * H_ + g] = hnew;
}

extern "C" void kernel_launch(void* const* d_in, const int* in_sizes, int n_in,
                              void* d_out, int out_size, void* d_ws, size_t ws_size,
                              hipStream_t stream) {
    const float* x    = (const float*)d_in[0];
    const float* Wih0 = (const float*)d_in[1];
    const float* Whh0 = (const float*)d_in[2];
    const float* bih0 = (const float*)d_in[3];
    const float* bhh0 = (const float*)d_in[4];
    const float* Wih1 = (const float*)d_in[5];
    const float* Whh1 = (const float*)d_in[6];
    const float* bih1 = (const float*)d_in[7];
    const float* bhh1 = (const float*)d_in[8];
    float* out = (float*)d_out;

    const size_t need = (size_t)BT_ * G4 * sizeof(float);   // 117,440,512 B
    if (ws_size >= need) {
        float* A = (float*)d_ws;
        proj_kernel<<<dim3(BT_ / PRB), dim3(256), 0, stream>>>(x, Wih0, bih0, bhh0, A);
        rec_kernel<<<dim3(B_ / 4), dim3(256), 0, stream>>>(A, Whh0, Wih1, Whh1,
                                                           bih1, bhh1, out);
    } else {
        lstm2_fallback<<<dim3(B_ / BPB), dim3(256), 0, stream>>>(
            x, Wih0, Whh0, bih0, bhh0, Wih1, Whh1, bih1, bhh1, out);
    }
}